// Round 4
// baseline (222.991 us; speedup 1.0000x reference)
//
#include <hip/hip_runtime.h>

#define B_ 4
#define C_ 64
#define H_ 256
#define W_ 256
#define HW_ (H_*W_)
#define MID_ 12
#define NPB_ 1024   // gap partial slots per image (= blocks per image: 4*256)

__device__ __forceinline__ float wave_reduce64(float v) {
#pragma unroll
    for (int off = 32; off; off >>= 1) v += __shfl_xor(v, off, 64);
    return v;
}

__device__ __forceinline__ void fnorm9(float* t9, const float* __restrict__ sstd) {
    float mean = 0.f;
#pragma unroll
    for (int t = 0; t < 9; ++t) mean += t9[t];
    mean *= (1.f / 9.f);
    float var = 0.f;
#pragma unroll
    for (int t = 0; t < 9; ++t) { float d = t9[t] - mean; var += d * d; }
    float inv = 1.f / (sqrtf(var * (1.f / 8.f)) + 1e-10f);
#pragma unroll
    for (int t = 0; t < 9; ++t) t9[t] = (t9[t] - mean) * inv * sstd[t];
}

// ---------------- prep: read x once -> s1 + gap1 partials ----------------
// block 256 = 4 waves; lane -> pixel (64-px strip), wave -> 16-channel group.
// grid (W/64, H, B) = 4096 blocks.
__global__ __launch_bounds__(256) void prep_kernel(const float* __restrict__ x,
    const float* __restrict__ sw, const float* __restrict__ sb,
    const float* __restrict__ sstd, float* __restrict__ sarr, float* __restrict__ gp) {
    const int lane = threadIdx.x & 63, wv = threadIdx.x >> 6;
    const int col = blockIdx.x * 64 + lane;
    const int row = blockIdx.y;
    const int b = blockIdx.z;
    const int c0 = wv * 16;
    const int bslot = blockIdx.y * gridDim.x + blockIdx.x;  // 0..NPB_-1
    __shared__ float lds[4][9][64];

    float st[9];
#pragma unroll
    for (int t = 0; t < 9; ++t) st[t] = 0.f;

    const float* xp = x + ((size_t)b * C_ + c0) * HW_ + (size_t)row * W_ + col;
    for (int i = 0; i < 16; ++i) {
        float v = xp[(size_t)i * HW_];
#pragma unroll
        for (int t = 0; t < 9; ++t) st[t] = fmaf(v, sw[t * C_ + c0 + i], st[t]);
        float g = wave_reduce64(v);
        if (lane == 0) gp[((size_t)b * C_ + c0 + i) * NPB_ + bslot] = g;
    }
#pragma unroll
    for (int t = 0; t < 9; ++t) lds[wv][t][lane] = st[t];
    __syncthreads();
    if (wv == 0) {
        float t9[9];
#pragma unroll
        for (int t = 0; t < 9; ++t)
            t9[t] = sb[t] + lds[0][t][lane] + lds[1][t][lane] + lds[2][t][lane] + lds[3][t][lane];
        fnorm9(t9, sstd);
        float* sp = sarr + ((size_t)b * 9) * HW_ + (size_t)row * W_ + col;
#pragma unroll
        for (int t = 0; t < 9; ++t) sp[(size_t)t * HW_] = t9[t];
    }
}

// ------ cfk: reduce gap partials + SE MLP + FilterNorm -> cf (B,C,12 padded) ------
__global__ __launch_bounds__(256) void cfk(const float* __restrict__ gp,
    const float* __restrict__ cw1, const float* __restrict__ cb1,
    const float* __restrict__ cw2, const float* __restrict__ cb2,
    const float* __restrict__ cstd, float* __restrict__ cf) {
    const int tid = threadIdx.x;
    const int b = tid >> 6, c = tid & 63;
    __shared__ float gsm[B_][C_];
    __shared__ float hsm[B_][MID_];
    {
        const float4* p4 = (const float4*)(gp + ((size_t)b * C_ + c) * NPB_);
        float s = 0.f;
        for (int i = 0; i < NPB_ / 4; ++i) { float4 v = p4[i]; s += (v.x + v.y) + (v.z + v.w); }
        gsm[b][c] = s * (1.f / HW_);
    }
    __syncthreads();
    if (tid < B_ * MID_) {
        int b2 = tid / MID_, m = tid % MID_;
        float a = cb1[m];
        for (int cc = 0; cc < C_; ++cc) a = fmaf(gsm[b2][cc], cw1[m * C_ + cc], a);
        hsm[b2][m] = fmaxf(a, 0.f);
    }
    __syncthreads();
    float v[9];
    float mean = 0.f;
#pragma unroll
    for (int t = 0; t < 9; ++t) {
        int o = c * 9 + t;
        float a = cb2[o];
#pragma unroll
        for (int m = 0; m < MID_; ++m) a = fmaf(hsm[b][m], cw2[o * MID_ + m], a);
        v[t] = a;
        mean += a;
    }
    mean *= (1.f / 9.f);
    float var = 0.f;
#pragma unroll
    for (int t = 0; t < 9; ++t) { float d = v[t] - mean; var += d * d; }
    float inv = 1.f / (sqrtf(var * (1.f / 8.f)) + 1e-10f);
    float* o12 = cf + ((size_t)b * C_ + c) * 12;
#pragma unroll
    for (int t = 0; t < 9; ++t) o12[t] = (v[t] - mean) * inv * cstd[c * 9 + t];
    o12[9] = 0.f; o12[10] = 0.f; o12[11] = 0.f;
}

// ---------- apply: patches * cf * s [PASS1: relu + s_next + gap | PASS2: +resid] ----------
// Same geometry as prep: block 4 waves x 64 lanes, grid (W/64, H, B).
template<bool PASS1>
__global__ __launch_bounds__(256) void apply_kernel(const float* __restrict__ in,
    const float* __restrict__ sarr, const float* __restrict__ cf,
    const float* __restrict__ swn, const float* __restrict__ sbn,
    const float* __restrict__ sstdn, const float* __restrict__ resid,
    float* __restrict__ out, float* __restrict__ snext, float* __restrict__ gpn) {
    const int lane = threadIdx.x & 63, wv = threadIdx.x >> 6;
    const int col = blockIdx.x * 64 + lane;
    const int row = blockIdx.y;
    const int b = blockIdx.z;
    const int c0 = wv * 16;
    const int bslot = blockIdx.y * gridDim.x + blockIdx.x;
    __shared__ float lds[4][9][64];

    // s at my pixel (9 taps)
    float s0[9];
    {
        const float* sp = sarr + ((size_t)b * 9) * HW_ + (size_t)row * W_ + col;
#pragma unroll
        for (int t = 0; t < 9; ++t) s0[t] = sp[(size_t)t * HW_];
    }
    float nt[9];
    if (PASS1) {
#pragma unroll
        for (int t = 0; t < 9; ++t) nt[t] = 0.f;
    }

    const bool rup = row > 0, rdn = row < H_ - 1;
    const bool cl = col > 0, cr = col < W_ - 1;
    const float* base = in + ((size_t)b * C_ + c0) * HW_ + (size_t)row * W_ + col;
    const float* cfb  = cf + ((size_t)b * C_ + c0) * 12;
    float* outp = out + ((size_t)b * C_ + c0) * HW_ + (size_t)row * W_ + col;
    const float* rb = PASS1 ? nullptr : (resid + ((size_t)b * C_ + c0) * HW_ + (size_t)row * W_ + col);

    for (int i = 0; i < 16; ++i) {
        const float4* cfv = (const float4*)(cfb + (size_t)i * 12);
        float4 ca = cfv[0], cb4 = cfv[1], cc4 = cfv[2];
        const float cw9[9] = {ca.x, ca.y, ca.z, ca.w, cb4.x, cb4.y, cb4.z, cb4.w, cc4.x};
        const float* p = base + (size_t)i * HW_;
        float acc = 0.f;
#pragma unroll
        for (int dr = 0; dr < 3; ++dr) {
            const bool rv = (dr == 0) ? rup : ((dr == 2) ? rdn : true);
            const float* rp = p + (dr - 1) * W_;
            float ml = (rv && cl) ? rp[-1] : 0.f;
            float mm = rv ? rp[0] : 0.f;
            float mr = (rv && cr) ? rp[1] : 0.f;
            const int t = dr * 3;
            acc = fmaf(ml * s0[t],     cw9[t],     acc);
            acc = fmaf(mm * s0[t + 1], cw9[t + 1], acc);
            acc = fmaf(mr * s0[t + 2], cw9[t + 2], acc);
        }
        float o;
        if (PASS1) {
            o = fmaxf(acc, 0.f);
#pragma unroll
            for (int t = 0; t < 9; ++t) nt[t] = fmaf(o, swn[t * C_ + c0 + i], nt[t]);
            float g = wave_reduce64(o);
            if (lane == 0) gpn[((size_t)b * C_ + c0 + i) * NPB_ + bslot] = g;
        } else {
            o = acc + rb[(size_t)i * HW_];
        }
        outp[(size_t)i * HW_] = o;
    }

    if (PASS1) {
#pragma unroll
        for (int t = 0; t < 9; ++t) lds[wv][t][lane] = nt[t];
        __syncthreads();
        if (wv == 0) {
            float t9[9];
#pragma unroll
            for (int t = 0; t < 9; ++t)
                t9[t] = sbn[t] + lds[0][t][lane] + lds[1][t][lane] + lds[2][t][lane] + lds[3][t][lane];
            fnorm9(t9, sstdn);
            float* sp = snext + ((size_t)b * 9) * HW_ + (size_t)row * W_ + col;
#pragma unroll
            for (int t = 0; t < 9; ++t) sp[(size_t)t * HW_] = t9[t];
        }
    }
}

// ================= fallback (round-1 path, smaller ws need) =================
__global__ __launch_bounds__(256) void gap_kernel(const float* __restrict__ in,
                                                  float* __restrict__ g) {
    int bc = blockIdx.x;
    const float4* p4 = (const float4*)(in + (size_t)bc * HW_);
    float sum = 0.f;
    for (int i = threadIdx.x; i < HW_ / 4; i += 256) {
        float4 v = p4[i];
        sum += (v.x + v.y) + (v.z + v.w);
    }
    __shared__ float red[256];
    red[threadIdx.x] = sum;
    __syncthreads();
    for (int s = 128; s > 0; s >>= 1) {
        if (threadIdx.x < s) red[threadIdx.x] += red[threadIdx.x + s];
        __syncthreads();
    }
    if (threadIdx.x == 0) g[bc] = red[0] * (1.0f / HW_);
}

__global__ __launch_bounds__(256) void cf_kernel(const float* __restrict__ g,
    const float* __restrict__ cw1, const float* __restrict__ cb1,
    const float* __restrict__ cw2, const float* __restrict__ cb2,
    const float* __restrict__ cstd, float* __restrict__ cf) {
    __shared__ float hsm[B_][MID_];
    int tid = threadIdx.x;
    if (tid < B_ * MID_) {
        int b = tid / MID_, m = tid % MID_;
        float acc = cb1[m];
        for (int c = 0; c < C_; ++c) acc = fmaf(g[b * C_ + c], cw1[m * C_ + c], acc);
        hsm[b][m] = fmaxf(acc, 0.f);
    }
    __syncthreads();
    int b = tid >> 6, c = tid & 63;
    float v[9];
    float mean = 0.f;
#pragma unroll
    for (int t = 0; t < 9; ++t) {
        int o = c * 9 + t;
        float acc = cb2[o];
#pragma unroll
        for (int m = 0; m < MID_; ++m) acc = fmaf(hsm[b][m], cw2[o * MID_ + m], acc);
        v[t] = acc;
        mean += acc;
    }
    mean *= (1.f / 9.f);
    float var = 0.f;
#pragma unroll
    for (int t = 0; t < 9; ++t) { float d = v[t] - mean; var += d * d; }
    float inv = 1.f / (sqrtf(var * (1.f / 8.f)) + 1e-10f);
#pragma unroll
    for (int t = 0; t < 9; ++t)
        cf[(b * C_ + c) * 9 + t] = (v[t] - mean) * inv * cstd[c * 9 + t];
}

template <bool RELU, bool RESID>
__global__ __launch_bounds__(256) void ddf_main(const float* __restrict__ in,
    const float* __restrict__ sw, const float* __restrict__ sb,
    const float* __restrict__ sstd, const float* __restrict__ cf,
    const float* __restrict__ resid, float* __restrict__ out) {
    const int tx = threadIdx.x & 63, ty = threadIdx.x >> 6;
    const int w = blockIdx.x * 64 + tx;
    const int h = blockIdx.y * 4 + ty;
    const int b = blockIdx.z;
    const float* xb = in + (size_t)b * C_ * HW_;
    float s[9];
#pragma unroll
    for (int t = 0; t < 9; ++t) s[t] = sb[t];
    {
        const float* xp = xb + h * W_ + w;
        for (int c = 0; c < C_; ++c) {
            float xv = xp[(size_t)c * HW_];
#pragma unroll
            for (int t = 0; t < 9; ++t) s[t] = fmaf(xv, sw[t * C_ + c], s[t]);
        }
    }
    float mean = 0.f;
#pragma unroll
    for (int t = 0; t < 9; ++t) mean += s[t];
    mean *= (1.f / 9.f);
    float var = 0.f;
#pragma unroll
    for (int t = 0; t < 9; ++t) { float d = s[t] - mean; var += d * d; }
    float inv = 1.f / (sqrtf(var * (1.f / 8.f)) + 1e-10f);
#pragma unroll
    for (int t = 0; t < 9; ++t) s[t] = (s[t] - mean) * inv * sstd[t];
    const bool rok0 = (h > 0), rok2 = (h < H_ - 1);
    const bool cok0 = (w > 0), cok2 = (w < W_ - 1);
    const float* cfb = cf + b * (C_ * 9);
    const size_t base = (size_t)h * W_ + w;
    const size_t bbase = (size_t)b * C_ * HW_ + base;
    for (int c = 0; c < C_; ++c) {
        const float* xc = xb + (size_t)c * HW_ + base;
        float acc = 0.f;
#pragma unroll
        for (int i = 0; i < 3; ++i) {
            const bool rok = (i == 0) ? rok0 : ((i == 2) ? rok2 : true);
#pragma unroll
            for (int j = 0; j < 3; ++j) {
                const bool cok = (j == 0) ? cok0 : ((j == 2) ? cok2 : true);
                float xv = (rok && cok) ? xc[(i - 1) * W_ + (j - 1)] : 0.f;
                acc = fmaf(xv, cfb[c * 9 + i * 3 + j] * s[i * 3 + j], acc);
            }
        }
        if (RELU) acc = fmaxf(acc, 0.f);
        size_t oidx = bbase + (size_t)c * HW_;
        if (RESID) acc += resid[oidx];
        out[oidx] = acc;
    }
}

extern "C" void kernel_launch(void* const* d_in, const int* in_sizes, int n_in,
                              void* d_out, int out_size, void* d_ws, size_t ws_size,
                              hipStream_t stream) {
    const float* x     = (const float*)d_in[0];
    const float* sw1   = (const float*)d_in[1];
    const float* sb1   = (const float*)d_in[2];
    const float* sstd1 = (const float*)d_in[3];
    const float* cw1_1 = (const float*)d_in[4];
    const float* cb1_1 = (const float*)d_in[5];
    const float* cw2_1 = (const float*)d_in[6];
    const float* cb2_1 = (const float*)d_in[7];
    const float* cstd1 = (const float*)d_in[8];
    const float* sw2   = (const float*)d_in[9];
    const float* sb2   = (const float*)d_in[10];
    const float* sstd2 = (const float*)d_in[11];
    const float* cw1_2 = (const float*)d_in[12];
    const float* cb1_2 = (const float*)d_in[13];
    const float* cw2_2 = (const float*)d_in[14];
    const float* cb2_2 = (const float*)d_in[15];
    const float* cstd2 = (const float*)d_in[16];
    float* outp = (float*)d_out;

    const size_t n_out1 = (size_t)B_ * C_ * HW_;     // 16,777,216
    const size_t n_s    = (size_t)B_ * 9 * HW_;      // 2,359,296
    const size_t n_cf   = (size_t)B_ * C_ * 12;      // 3,072 (padded)
    const size_t n_gp   = (size_t)B_ * C_ * NPB_;    // 262,144
    const size_t need_new = (n_out1 + 2 * n_s + 2 * n_cf + 2 * n_gp) * sizeof(float);

    if (ws_size >= need_new) {
        float* out1 = (float*)d_ws;
        float* s1   = out1 + n_out1;
        float* s2   = s1 + n_s;
        float* cf1  = s2 + n_s;
        float* cf2  = cf1 + n_cf;
        float* gp1  = cf2 + n_cf;
        float* gp2  = gp1 + n_gp;

        dim3 g(W_ / 64, H_, B_);   // 4096 blocks of 4 waves

        prep_kernel<<<g, 256, 0, stream>>>(x, sw1, sb1, sstd1, s1, gp1);
        cfk<<<1, 256, 0, stream>>>(gp1, cw1_1, cb1_1, cw2_1, cb2_1, cstd1, cf1);
        apply_kernel<true><<<g, 256, 0, stream>>>(x, s1, cf1, sw2, sb2, sstd2,
                                                  nullptr, out1, s2, gp2);
        cfk<<<1, 256, 0, stream>>>(gp2, cw1_2, cb1_2, cw2_2, cb2_2, cstd2, cf2);
        apply_kernel<false><<<g, 256, 0, stream>>>(out1, s2, cf2, nullptr, nullptr,
                                                   nullptr, x, outp, nullptr, nullptr);
        return;
    }

    // fallback (round-1 structure)
    const size_t need_old = (n_out1 + 256 + (size_t)B_ * C_ * 9) * sizeof(float);
    if (ws_size < need_old) return;
    float* out1 = (float*)d_ws;
    float* gg   = out1 + n_out1;
    float* cfb  = gg + 256;
    dim3 grid(W_ / 64, H_ / 4, B_);
    gap_kernel<<<B_ * C_, 256, 0, stream>>>(x, gg);
    cf_kernel<<<1, 256, 0, stream>>>(gg, cw1_1, cb1_1, cw2_1, cb2_1, cstd1, cfb);
    ddf_main<true, false><<<grid, 256, 0, stream>>>(x, sw1, sb1, sstd1, cfb, nullptr, out1);
    gap_kernel<<<B_ * C_, 256, 0, stream>>>(out1, gg);
    cf_kernel<<<1, 256, 0, stream>>>(gg, cw1_2, cb1_2, cw2_2, cb2_2, cstd2, cfb);
    ddf_main<false, true><<<grid, 256, 0, stream>>>(out1, sw2, sb2, sstd2, cfb, x, outp);
}

// Round 5
// 180.322 us; speedup vs baseline: 1.2366x; 1.2366x over previous
//
#include <hip/hip_runtime.h>

#define B_ 4
#define C_ 64
#define H_ 256
#define W_ 256
#define HW_ (H_*W_)
#define MID_ 12
#define NPB_ 256   // gap partial slots per image (= blocks per image: 4*64)

__device__ __forceinline__ float wave_reduce64(float v) {
#pragma unroll
    for (int off = 32; off; off >>= 1) v += __shfl_xor(v, off, 64);
    return v;
}

__device__ __forceinline__ void fnorm9(float* t9, const float* __restrict__ sstd) {
    float mean = 0.f;
#pragma unroll
    for (int t = 0; t < 9; ++t) mean += t9[t];
    mean *= (1.f / 9.f);
    float var = 0.f;
#pragma unroll
    for (int t = 0; t < 9; ++t) { float d = t9[t] - mean; var += d * d; }
    float inv = 1.f / (sqrtf(var * (1.f / 8.f)) + 1e-10f);
#pragma unroll
    for (int t = 0; t < 9; ++t) t9[t] = (t9[t] - mean) * inv * sstd[t];
}

// ---------------- prep: read x once -> s1 + gap1 partials ----------------
// block 256 = 4 waves; lane -> col (64-strip), wave -> row (4-row tile).
// Each thread covers ALL 64 channels at its pixel. grid (W/64, H/4, B) = 1024.
__global__ __launch_bounds__(256, 4) void prep_kernel(const float* __restrict__ x,
    const float* __restrict__ sw, const float* __restrict__ sb,
    const float* __restrict__ sstd, float* __restrict__ sarr, float* __restrict__ gp) {
    const int lane = threadIdx.x & 63, wv = threadIdx.x >> 6;
    const int col = blockIdx.x * 64 + lane;
    const int row = blockIdx.y * 4 + wv;
    const int b = blockIdx.z;
    const int bslot = blockIdx.y * gridDim.x + blockIdx.x;  // 0..NPB_-1
    __shared__ float lg[4][C_];

    float st[9];
#pragma unroll
    for (int t = 0; t < 9; ++t) st[t] = sb[t];

    const float* xp = x + ((size_t)b * C_) * HW_ + (size_t)row * W_ + col;
#pragma unroll 8
    for (int c = 0; c < C_; ++c) {
        float v = xp[(size_t)c * HW_];
#pragma unroll
        for (int t = 0; t < 9; ++t) st[t] = fmaf(v, sw[t * C_ + c], st[t]);
        float g = wave_reduce64(v);
        if (lane == 0) lg[wv][c] = g;
    }
    fnorm9(st, sstd);
    {
        float* sp = sarr + ((size_t)b * 9) * HW_ + (size_t)row * W_ + col;
#pragma unroll
        for (int t = 0; t < 9; ++t) sp[(size_t)t * HW_] = st[t];
    }
    __syncthreads();
    if (threadIdx.x < C_) {
        int c = threadIdx.x;
        float s4 = lg[0][c] + lg[1][c] + lg[2][c] + lg[3][c];
        gp[((size_t)b * C_ + c) * NPB_ + bslot] = s4;
    }
}

// ------ cfk: reduce gap partials + SE MLP + FilterNorm -> cf (B,C,12 padded) ------
__global__ __launch_bounds__(256) void cfk(const float* __restrict__ gp,
    const float* __restrict__ cw1, const float* __restrict__ cb1,
    const float* __restrict__ cw2, const float* __restrict__ cb2,
    const float* __restrict__ cstd, float* __restrict__ cf) {
    const int tid = threadIdx.x;
    const int b = tid >> 6, c = tid & 63;
    __shared__ float gsm[B_][C_];
    __shared__ float hsm[B_][MID_];
    {
        const float4* p4 = (const float4*)(gp + ((size_t)b * C_ + c) * NPB_);
        float s = 0.f;
#pragma unroll 4
        for (int i = 0; i < NPB_ / 4; ++i) { float4 v = p4[i]; s += (v.x + v.y) + (v.z + v.w); }
        gsm[b][c] = s * (1.f / HW_);
    }
    __syncthreads();
    if (tid < B_ * MID_) {
        int b2 = tid / MID_, m = tid % MID_;
        float a = cb1[m];
        for (int cc = 0; cc < C_; ++cc) a = fmaf(gsm[b2][cc], cw1[m * C_ + cc], a);
        hsm[b2][m] = fmaxf(a, 0.f);
    }
    __syncthreads();
    float v[9];
    float mean = 0.f;
#pragma unroll
    for (int t = 0; t < 9; ++t) {
        int o = c * 9 + t;
        float a = cb2[o];
#pragma unroll
        for (int m = 0; m < MID_; ++m) a = fmaf(hsm[b][m], cw2[o * MID_ + m], a);
        v[t] = a;
        mean += a;
    }
    mean *= (1.f / 9.f);
    float var = 0.f;
#pragma unroll
    for (int t = 0; t < 9; ++t) { float d = v[t] - mean; var += d * d; }
    float inv = 1.f / (sqrtf(var * (1.f / 8.f)) + 1e-10f);
    float* o12 = cf + ((size_t)b * C_ + c) * 12;
#pragma unroll
    for (int t = 0; t < 9; ++t) o12[t] = (v[t] - mean) * inv * cstd[c * 9 + t];
    o12[9] = 0.f; o12[10] = 0.f; o12[11] = 0.f;
}

// ---------- apply: patches * cf * s [PASS1: relu + s_next + gap | PASS2: +resid] ----------
// Same geometry as prep: lane->col, wave->row, all 64 channels. grid (4, 64, B).
template<bool PASS1>
__global__ __launch_bounds__(256, 4) void apply_kernel(const float* __restrict__ in,
    const float* __restrict__ sarr, const float* __restrict__ cf,
    const float* __restrict__ swn, const float* __restrict__ sbn,
    const float* __restrict__ sstdn, const float* __restrict__ resid,
    float* __restrict__ out, float* __restrict__ snext, float* __restrict__ gpn) {
    const int lane = threadIdx.x & 63, wv = threadIdx.x >> 6;
    const int col = blockIdx.x * 64 + lane;
    const int row = blockIdx.y * 4 + wv;
    const int b = blockIdx.z;
    const int bslot = blockIdx.y * gridDim.x + blockIdx.x;
    __shared__ float lg[4][C_];

    // s at my pixel (9 taps)
    float s0[9];
    {
        const float* sp = sarr + ((size_t)b * 9) * HW_ + (size_t)row * W_ + col;
#pragma unroll
        for (int t = 0; t < 9; ++t) s0[t] = sp[(size_t)t * HW_];
    }
    float nt[9];
    if (PASS1) {
#pragma unroll
        for (int t = 0; t < 9; ++t) nt[t] = sbn[t];
    }

    const bool rup = row > 0, rdn = row < H_ - 1;
    const bool cl = col > 0, cr = col < W_ - 1;
    const size_t pix = (size_t)row * W_ + col;
    const float* base = in + ((size_t)b * C_) * HW_ + pix;
    const float* cfb  = cf + ((size_t)b * C_) * 12;
    float* outp = out + ((size_t)b * C_) * HW_ + pix;
    const float* rb = PASS1 ? nullptr : (resid + ((size_t)b * C_) * HW_ + pix);

#pragma unroll 4
    for (int c = 0; c < C_; ++c) {
        const float4* cfv = (const float4*)(cfb + (size_t)c * 12);
        float4 ca = cfv[0], cb4 = cfv[1], cc4 = cfv[2];
        const float cw9[9] = {ca.x, ca.y, ca.z, ca.w, cb4.x, cb4.y, cb4.z, cb4.w, cc4.x};
        const float* p = base + (size_t)c * HW_;
        // batch all 9 patch loads (independent -> in flight together)
        const float* ru = p - W_;
        const float* rd = p + W_;
        float m00 = (rup && cl) ? ru[-1] : 0.f;
        float m01 = rup ? ru[0] : 0.f;
        float m02 = (rup && cr) ? ru[1] : 0.f;
        float m10 = cl ? p[-1] : 0.f;
        float m11 = p[0];
        float m12 = cr ? p[1] : 0.f;
        float m20 = (rdn && cl) ? rd[-1] : 0.f;
        float m21 = rdn ? rd[0] : 0.f;
        float m22 = (rdn && cr) ? rd[1] : 0.f;
        float acc = 0.f;
        acc = fmaf(m00 * s0[0], cw9[0], acc);
        acc = fmaf(m01 * s0[1], cw9[1], acc);
        acc = fmaf(m02 * s0[2], cw9[2], acc);
        acc = fmaf(m10 * s0[3], cw9[3], acc);
        acc = fmaf(m11 * s0[4], cw9[4], acc);
        acc = fmaf(m12 * s0[5], cw9[5], acc);
        acc = fmaf(m20 * s0[6], cw9[6], acc);
        acc = fmaf(m21 * s0[7], cw9[7], acc);
        acc = fmaf(m22 * s0[8], cw9[8], acc);
        float o;
        if (PASS1) {
            o = fmaxf(acc, 0.f);
#pragma unroll
            for (int t = 0; t < 9; ++t) nt[t] = fmaf(o, swn[t * C_ + c], nt[t]);
            float g = wave_reduce64(o);
            if (lane == 0) lg[wv][c] = g;
        } else {
            o = acc + rb[(size_t)c * HW_];
        }
        outp[(size_t)c * HW_] = o;
    }

    if (PASS1) {
        fnorm9(nt, sstdn);
        {
            float* sp = snext + ((size_t)b * 9) * HW_ + pix;
#pragma unroll
            for (int t = 0; t < 9; ++t) sp[(size_t)t * HW_] = nt[t];
        }
        __syncthreads();
        if (threadIdx.x < C_) {
            int c = threadIdx.x;
            float s4 = lg[0][c] + lg[1][c] + lg[2][c] + lg[3][c];
            gpn[((size_t)b * C_ + c) * NPB_ + bslot] = s4;
        }
    }
}

extern "C" void kernel_launch(void* const* d_in, const int* in_sizes, int n_in,
                              void* d_out, int out_size, void* d_ws, size_t ws_size,
                              hipStream_t stream) {
    const float* x     = (const float*)d_in[0];
    const float* sw1   = (const float*)d_in[1];
    const float* sb1   = (const float*)d_in[2];
    const float* sstd1 = (const float*)d_in[3];
    const float* cw1_1 = (const float*)d_in[4];
    const float* cb1_1 = (const float*)d_in[5];
    const float* cw2_1 = (const float*)d_in[6];
    const float* cb2_1 = (const float*)d_in[7];
    const float* cstd1 = (const float*)d_in[8];
    const float* sw2   = (const float*)d_in[9];
    const float* sb2   = (const float*)d_in[10];
    const float* sstd2 = (const float*)d_in[11];
    const float* cw1_2 = (const float*)d_in[12];
    const float* cb1_2 = (const float*)d_in[13];
    const float* cw2_2 = (const float*)d_in[14];
    const float* cb2_2 = (const float*)d_in[15];
    const float* cstd2 = (const float*)d_in[16];
    float* outp = (float*)d_out;

    const size_t n_out1 = (size_t)B_ * C_ * HW_;     // 16,777,216
    const size_t n_s    = (size_t)B_ * 9 * HW_;      // 2,359,296
    const size_t n_cf   = (size_t)B_ * C_ * 12;      // 3,072 (padded)
    const size_t n_gp   = (size_t)B_ * C_ * NPB_;    // 65,536
    const size_t need = (n_out1 + 2 * n_s + 2 * n_cf + 2 * n_gp) * sizeof(float);
    if (ws_size < need) return;

    float* out1 = (float*)d_ws;
    float* s1   = out1 + n_out1;
    float* s2   = s1 + n_s;
    float* cf1  = s2 + n_s;
    float* cf2  = cf1 + n_cf;
    float* gp1  = cf2 + n_cf;
    float* gp2  = gp1 + n_gp;

    dim3 g(W_ / 64, H_ / 4, B_);   // 1024 blocks of 4 waves

    prep_kernel<<<g, 256, 0, stream>>>(x, sw1, sb1, sstd1, s1, gp1);
    cfk<<<1, 256, 0, stream>>>(gp1, cw1_1, cb1_1, cw2_1, cb2_1, cstd1, cf1);
    apply_kernel<true><<<g, 256, 0, stream>>>(x, s1, cf1, sw2, sb2, sstd2,
                                              nullptr, out1, s2, gp2);
    cfk<<<1, 256, 0, stream>>>(gp2, cw1_2, cb1_2, cw2_2, cb2_2, cstd2, cf2);
    apply_kernel<false><<<g, 256, 0, stream>>>(out1, s2, cf2, nullptr, nullptr,
                                               nullptr, x, outp, nullptr, nullptr);
}

// Round 6
// 151.782 us; speedup vs baseline: 1.4691x; 1.1880x over previous
//
#include <hip/hip_runtime.h>

#define B_ 4
#define C_ 64
#define H_ 256
#define W_ 256
#define HW_ (H_*W_)
#define MID_ 12
#define NPB_ 256   // gap partial slots per image (= blocks per image: 4*64)

__device__ __forceinline__ float wave_reduce64(float v) {
#pragma unroll
    for (int off = 32; off; off >>= 1) v += __shfl_xor(v, off, 64);
    return v;
}

__device__ __forceinline__ void fnorm9(float* t9, const float* __restrict__ sstd) {
    float mean = 0.f;
#pragma unroll
    for (int t = 0; t < 9; ++t) mean += t9[t];
    mean *= (1.f / 9.f);
    float var = 0.f;
#pragma unroll
    for (int t = 0; t < 9; ++t) { float d = t9[t] - mean; var += d * d; }
    float inv = 1.f / (sqrtf(var * (1.f / 8.f)) + 1e-10f);
#pragma unroll
    for (int t = 0; t < 9; ++t) t9[t] = (t9[t] - mean) * inv * sstd[t];
}

// ---------------- prep: read x once -> s1 + gap1 partials ----------------
// block 256 = 4 waves; lane -> col (64-strip), wave -> row. grid (4, 64, B) = 1024.
__global__ __launch_bounds__(256) void prep_kernel(const float* __restrict__ x,
    const float* __restrict__ sw, const float* __restrict__ sb,
    const float* __restrict__ sstd, float* __restrict__ sarr, float* __restrict__ gp) {
    const int lane = threadIdx.x & 63, wv = threadIdx.x >> 6;
    const int col = blockIdx.x * 64 + lane;
    const int row = blockIdx.y * 4 + wv;
    const int b = blockIdx.z;
    const int bslot = blockIdx.y * gridDim.x + blockIdx.x;  // 0..NPB_-1
    const int pix = row * W_ + col;
    __shared__ float lg[4][C_];

    float st[9];
#pragma unroll
    for (int t = 0; t < 9; ++t) st[t] = sb[t];

    const float* xb = x + (size_t)b * C_ * HW_;   // wave-uniform base
    float vA[8], vB[8];
#pragma unroll
    for (int i = 0; i < 8; ++i) vA[i] = xb[(size_t)i * HW_ + pix];

    for (int c8 = 0; c8 < C_; c8 += 16) {
#pragma unroll
        for (int i = 0; i < 8; ++i) vB[i] = xb[(size_t)(c8 + 8 + i) * HW_ + pix];
#pragma unroll
        for (int i = 0; i < 8; ++i) {
#pragma unroll
            for (int t = 0; t < 9; ++t) st[t] = fmaf(vA[i], sw[t * C_ + c8 + i], st[t]);
            float g = wave_reduce64(vA[i]);
            if (lane == 0) lg[wv][c8 + i] = g;
        }
        if (c8 + 16 < C_) {
#pragma unroll
            for (int i = 0; i < 8; ++i) vA[i] = xb[(size_t)(c8 + 16 + i) * HW_ + pix];
        }
#pragma unroll
        for (int i = 0; i < 8; ++i) {
#pragma unroll
            for (int t = 0; t < 9; ++t) st[t] = fmaf(vB[i], sw[t * C_ + c8 + 8 + i], st[t]);
            float g = wave_reduce64(vB[i]);
            if (lane == 0) lg[wv][c8 + 8 + i] = g;
        }
    }
    fnorm9(st, sstd);
    {
        float* sp = sarr + ((size_t)b * 9) * HW_ + pix;
#pragma unroll
        for (int t = 0; t < 9; ++t) sp[(size_t)t * HW_] = st[t];
    }
    __syncthreads();
    if (threadIdx.x < C_) {
        int c = threadIdx.x;
        float s4 = lg[0][c] + lg[1][c] + lg[2][c] + lg[3][c];
        gp[((size_t)b * C_ + c) * NPB_ + bslot] = s4;
    }
}

// ------ cfk: reduce gap partials + SE MLP + FilterNorm -> cf (B,C,12 padded) ------
__global__ __launch_bounds__(256) void cfk(const float* __restrict__ gp,
    const float* __restrict__ cw1, const float* __restrict__ cb1,
    const float* __restrict__ cw2, const float* __restrict__ cb2,
    const float* __restrict__ cstd, float* __restrict__ cf) {
    const int tid = threadIdx.x;
    const int b = tid >> 6, c = tid & 63;
    __shared__ float gsm[B_][C_];
    __shared__ float hsm[B_][MID_];
    {
        const float4* p4 = (const float4*)(gp + ((size_t)b * C_ + c) * NPB_);
        float s = 0.f;
#pragma unroll 4
        for (int i = 0; i < NPB_ / 4; ++i) { float4 v = p4[i]; s += (v.x + v.y) + (v.z + v.w); }
        gsm[b][c] = s * (1.f / HW_);
    }
    __syncthreads();
    if (tid < B_ * MID_) {
        int b2 = tid / MID_, m = tid % MID_;
        float a = cb1[m];
        for (int cc = 0; cc < C_; ++cc) a = fmaf(gsm[b2][cc], cw1[m * C_ + cc], a);
        hsm[b2][m] = fmaxf(a, 0.f);
    }
    __syncthreads();
    float v[9];
    float mean = 0.f;
#pragma unroll
    for (int t = 0; t < 9; ++t) {
        int o = c * 9 + t;
        float a = cb2[o];
#pragma unroll
        for (int m = 0; m < MID_; ++m) a = fmaf(hsm[b][m], cw2[o * MID_ + m], a);
        v[t] = a;
        mean += a;
    }
    mean *= (1.f / 9.f);
    float var = 0.f;
#pragma unroll
    for (int t = 0; t < 9; ++t) { float d = v[t] - mean; var += d * d; }
    float inv = 1.f / (sqrtf(var * (1.f / 8.f)) + 1e-10f);
    float* o12 = cf + ((size_t)b * C_ + c) * 12;
#pragma unroll
    for (int t = 0; t < 9; ++t) o12[t] = (v[t] - mean) * inv * cstd[c * 9 + t];
    o12[9] = 0.f; o12[10] = 0.f; o12[11] = 0.f;
}

// ---------- apply: patches * cf * s [PASS1: relu + s_next + gap | PASS2: +resid] ----------
// lane->col, wave->row, all 64 channels/thread, software-pipelined depth-2.
// grid (4, 64, B) = 1024 blocks.
template<bool PASS1>
__global__ __launch_bounds__(256) void apply_kernel(const float* __restrict__ in,
    const float* __restrict__ sarr, const float* __restrict__ cf,
    const float* __restrict__ swn, const float* __restrict__ sbn,
    const float* __restrict__ sstdn, const float* __restrict__ resid,
    float* __restrict__ out, float* __restrict__ snext, float* __restrict__ gpn) {
    const int lane = threadIdx.x & 63, wv = threadIdx.x >> 6;
    const int col = blockIdx.x * 64 + lane;
    const int row = blockIdx.y * 4 + wv;
    const int b = blockIdx.z;
    const int bslot = blockIdx.y * gridDim.x + blockIdx.x;
    const int pix = row * W_ + col;
    __shared__ float lg[4][C_];

    // s at my pixel (9 taps), with OOB mask folded in
    float s0m[9];
    int off9[9];
    {
        const float* sp = sarr + ((size_t)b * 9) * HW_ + pix;
#pragma unroll
        for (int t = 0; t < 9; ++t) s0m[t] = sp[(size_t)t * HW_];
#pragma unroll
        for (int dr = -1; dr <= 1; ++dr)
#pragma unroll
            for (int dc = -1; dc <= 1; ++dc) {
                const int t = (dr + 1) * 3 + (dc + 1);
                const bool ok = (row + dr >= 0) && (row + dr < H_) &&
                                (col + dc >= 0) && (col + dc < W_);
                off9[t] = ok ? (pix + dr * W_ + dc) : pix;
                if (!ok) s0m[t] = 0.f;
            }
    }
    float nt[9];
    if (PASS1) {
#pragma unroll
        for (int t = 0; t < 9; ++t) nt[t] = sbn[t];
    }

    const float* inb = in + (size_t)b * C_ * HW_;          // wave-uniform
    const float* cfb = cf + ((size_t)b * C_) * 12;         // wave-uniform
    const float* rb  = PASS1 ? nullptr : (resid + (size_t)b * C_ * HW_);
    float* outp = out + (size_t)b * C_ * HW_;

    float mA[9], mB[9], rA = 0.f, rB = 0.f;

#define LOAD9(M, RV, cc) do {                                        \
        const float* cbp_ = inb + (size_t)(cc) * HW_;                \
        _Pragma("unroll")                                            \
        for (int t_ = 0; t_ < 9; ++t_) M[t_] = cbp_[off9[t_]];       \
        if (!PASS1) RV = rb[(size_t)(cc) * HW_ + pix];               \
    } while (0)

#define COMPUTE(M, RV, cc) do {                                      \
        const float* cfc_ = cfb + (size_t)(cc) * 12;                 \
        float acc_ = 0.f;                                            \
        _Pragma("unroll")                                            \
        for (int t_ = 0; t_ < 9; ++t_)                               \
            acc_ = fmaf(M[t_] * s0m[t_], cfc_[t_], acc_);            \
        float o_;                                                    \
        if (PASS1) {                                                 \
            o_ = fmaxf(acc_, 0.f);                                   \
            _Pragma("unroll")                                        \
            for (int t_ = 0; t_ < 9; ++t_)                           \
                nt[t_] = fmaf(o_, swn[t_ * C_ + (cc)], nt[t_]);      \
            float g_ = wave_reduce64(o_);                            \
            if (lane == 0) lg[wv][cc] = g_;                          \
        } else {                                                     \
            o_ = acc_ + RV;                                          \
        }                                                            \
        outp[(size_t)(cc) * HW_ + pix] = o_;                         \
    } while (0)

    LOAD9(mA, rA, 0);
    for (int c = 0; c < C_; c += 2) {
        LOAD9(mB, rB, c + 1);
        COMPUTE(mA, rA, c);
        if (c + 2 < C_) LOAD9(mA, rA, c + 2);
        COMPUTE(mB, rB, c + 1);
    }
#undef LOAD9
#undef COMPUTE

    if (PASS1) {
        fnorm9(nt, sstdn);
        {
            float* sp = snext + ((size_t)b * 9) * HW_ + pix;
#pragma unroll
            for (int t = 0; t < 9; ++t) sp[(size_t)t * HW_] = nt[t];
        }
        __syncthreads();
        if (threadIdx.x < C_) {
            int c = threadIdx.x;
            float s4 = lg[0][c] + lg[1][c] + lg[2][c] + lg[3][c];
            gpn[((size_t)b * C_ + c) * NPB_ + bslot] = s4;
        }
    }
}

extern "C" void kernel_launch(void* const* d_in, const int* in_sizes, int n_in,
                              void* d_out, int out_size, void* d_ws, size_t ws_size,
                              hipStream_t stream) {
    const float* x     = (const float*)d_in[0];
    const float* sw1   = (const float*)d_in[1];
    const float* sb1   = (const float*)d_in[2];
    const float* sstd1 = (const float*)d_in[3];
    const float* cw1_1 = (const float*)d_in[4];
    const float* cb1_1 = (const float*)d_in[5];
    const float* cw2_1 = (const float*)d_in[6];
    const float* cb2_1 = (const float*)d_in[7];
    const float* cstd1 = (const float*)d_in[8];
    const float* sw2   = (const float*)d_in[9];
    const float* sb2   = (const float*)d_in[10];
    const float* sstd2 = (const float*)d_in[11];
    const float* cw1_2 = (const float*)d_in[12];
    const float* cb1_2 = (const float*)d_in[13];
    const float* cw2_2 = (const float*)d_in[14];
    const float* cb2_2 = (const float*)d_in[15];
    const float* cstd2 = (const float*)d_in[16];
    float* outp = (float*)d_out;

    const size_t n_out1 = (size_t)B_ * C_ * HW_;     // 16,777,216
    const size_t n_s    = (size_t)B_ * 9 * HW_;      // 2,359,296
    const size_t n_cf   = (size_t)B_ * C_ * 12;      // 3,072 (padded)
    const size_t n_gp   = (size_t)B_ * C_ * NPB_;    // 65,536
    const size_t need = (n_out1 + 2 * n_s + 2 * n_cf + 2 * n_gp) * sizeof(float);
    if (ws_size < need) return;

    float* out1 = (float*)d_ws;
    float* s1   = out1 + n_out1;
    float* s2   = s1 + n_s;
    float* cf1  = s2 + n_s;
    float* cf2  = cf1 + n_cf;
    float* gp1  = cf2 + n_cf;
    float* gp2  = gp1 + n_gp;

    dim3 g(W_ / 64, H_ / 4, B_);   // 1024 blocks of 4 waves

    prep_kernel<<<g, 256, 0, stream>>>(x, sw1, sb1, sstd1, s1, gp1);
    cfk<<<1, 256, 0, stream>>>(gp1, cw1_1, cb1_1, cw2_1, cb2_1, cstd1, cf1);
    apply_kernel<true><<<g, 256, 0, stream>>>(x, s1, cf1, sw2, sb2, sstd2,
                                              nullptr, out1, s2, gp2);
    cfk<<<1, 256, 0, stream>>>(gp2, cw1_2, cb1_2, cw2_2, cb2_2, cstd2, cf2);
    apply_kernel<false><<<g, 256, 0, stream>>>(out1, s2, cf2, nullptr, nullptr,
                                               nullptr, x, outp, nullptr, nullptr);
}